// Round 5
// baseline (60.032 us; speedup 1.0000x reference)
//
#include <hip/hip_runtime.h>
#include <stdint.h>

typedef unsigned short u16;
typedef __attribute__((ext_vector_type(4))) float f32x4;
typedef __attribute__((ext_vector_type(8))) __bf16 bf16x8;

// ---- Cayley table for Cl(3,0), basis order [1,e1,e2,e3,e12,e13,e23,e123] ----
struct Cay { int idx[8][8]; float sgn[8][8]; };
constexpr int kOrder[8] = {0,1,2,4,3,5,6,7};
constexpr int ordpos(int m){ int r=-1; for(int i=0;i<8;i++) if(kOrder[i]==m) r=i; return r; }
constexpr Cay make_cay(){
  Cay c{};
  for(int ia=0; ia<8; ia++) for(int ib=0; ib<8; ib++){
    int a=kOrder[ia], b=kOrder[ib];
    int t=a>>1, tot=0;
    while(t){ int x=t&b; while(x){ tot+=x&1; x>>=1; } t>>=1; }
    c.idx[ia][ib]=ordpos(a^b);
    c.sgn[ia][ib]=(tot&1)?-1.0f:1.0f;
  }
  return c;
}
constexpr Cay CAY = make_cay();

// ---- squared-multivector GP at HALF SCALE for k!=0 (x2 folded into W2 grades 1..3) ----
struct GPTab { float dsgn[8]; int np; int pi[28]; int pj[28]; int pk[28]; float ps[28]; };
constexpr GPTab make_gptab(){
  GPTab t{};
  for (int i=0;i<8;i++) t.dsgn[i] = CAY.sgn[i][i];
  t.np = 0;
  for (int i=0;i<8;i++) for (int j=i+1;j<8;j++){
    float s = CAY.sgn[i][j] + CAY.sgn[j][i];      // in {-2,0,+2}
    if (s != 0.0f){ t.pi[t.np]=i; t.pj[t.np]=j; t.pk[t.np]=CAY.idx[i][j];
                    t.ps[t.np]=(s>0.f)?1.0f:-1.0f; t.np++; }
  }
  return t;
}
constexpr GPTab GPT = make_gptab();

__device__ __forceinline__ void gprod_half(const float* h, float* g){
  float g0 = h[0]*h[0];
  #pragma unroll
  for (int i=1;i<8;i++) g0 = fmaf(GPT.dsgn[i]>0.f ? h[i] : -h[i], h[i], g0);
  g[0] = g0;
  #pragma unroll
  for (int k=1;k<8;k++) g[k] = 0.f;
  #pragma unroll
  for (int t=0;t<GPT.np;t++)
    g[GPT.pk[t]] = fmaf(GPT.ps[t]>0.f ? h[GPT.pi[t]] : -h[GPT.pi[t]],
                        h[GPT.pj[t]], g[GPT.pk[t]]);
}

__device__ __forceinline__ u16 f2bf(float f){
  union { float f; uint32_t u; } v; v.f=f;
  uint32_t u=v.u;
  return (u16)((u + 0x7fffu + ((u>>16)&1u)) >> 16);   // RNE
}

__device__ __forceinline__ uint32_t cvtpk(float lo, float hi){
  uint32_t r;
  asm("v_cvt_pk_bf16_f32 %0, %1, %2" : "=v"(r) : "v"(lo), "v"(hi));
  return r;
}

__device__ __forceinline__ float fc(const float4& v, int c){
  switch(c){ case 0: return v.x; case 1: return v.y; case 2: return v.z; default: return v.w; }
}

// ---- weight repack ----
// w1p frag f=((g*2+ks)*8+ot): lane l, elem e -> W1[ot*16+(l&15)][ks*32+(l>>4)*8+e][g]
// w2p frag f=((g*4+ks)*4+ot): lane l, elem e -> W2[ot*16+(l&15)][ks*32+(l>>4)*8+e][g] * (g?2:1)
__global__ void gp_prepack(const float* __restrict__ W1, const float* __restrict__ W2,
                           u16* __restrict__ w1p, u16* __restrict__ w2p)
{
  int t = blockIdx.x*256 + threadIdx.x;   // 0..65535
  int e = t & 7, l = (t>>3)&63, f = t>>9;
  int lm = l & 15, lh = l >> 4;
  if (f < 64) {
    int g = f >> 4, ks = (f>>3)&1, ot = f&7;
    int o = ot*16 + lm, c = ks*32 + lh*8 + e;
    w1p[f*512 + l*8 + e] = f2bf(W1[(o*64 + c)*4 + g]);
  } else {
    int f2 = f - 64;
    int g = f2 >> 4, ks = (f2>>2)&3, ot = f2&3;
    int outc = ot*16 + lm, o = ks*32 + lh*8 + e;
    float sc = (g == 0) ? 1.0f : 2.0f;               // half-scale GP compensation
    w2p[f2*512 + l*8 + e] = f2bf(W2[(outc*128 + o)*4 + g] * sc);
  }
}

// LDS = G tile only: [pos16][blade8][ch128] bf16 = 32768 B, swizzle byte ^= ((pos&7)<<4).
// redArr[16][4] aliases SH+0 after stage-2 reads complete.
// Stage-1 B-fragments come DIRECTLY from global (k = c identity permutation):
//   lane (lm,lh) reads x[pos=lm][c = ks*32+lh*8+e][blade 0..7] — 2 contiguous 256B runs.
__global__ __launch_bounds__(256,4) void gp_fused(
    const float* __restrict__ x, const u16* __restrict__ w1p,
    const float* __restrict__ b1, const u16* __restrict__ w2p,
    const float* __restrict__ b2, const float* __restrict__ avec,
    float* __restrict__ out)
{
  __shared__ __align__(16) char SH[32768];
  float* redArr = reinterpret_cast<float*>(SH);     // [pos][w], 16x4 floats (aliases G, used post-bar)

  const int tid = threadIdx.x;
  const int w  = tid >> 6;     // wave 0..3
  const int l  = tid & 63;
  const int lm = l & 15;
  const int lh = l >> 4;
  const int xk = (lm & 7) << 4;   // LDS swizzle key (pos = lm)

  constexpr int BSTART[4] = {0,1,4,7};
  constexpr int BCNT[4]   = {1,3,3,1};

  // ---- direct global load of this lane's B-fragment data (no LDS, no barrier) ----
  // float4 index: pos*128 + lh*16 + ks*64 + i, i=0..15
  const float4* px = reinterpret_cast<const float4*>(x)
                   + ((size_t)blockIdx.x*16 + lm)*128 + lh*16;
  float4 va[16], vb[16];
  #pragma unroll
  for (int i=0;i<16;++i) va[i] = px[i];        // ks=0: c = lh*8 + e
  #pragma unroll
  for (int i=0;i<16;++i) vb[i] = px[64+i];     // ks=1: c = 32 + lh*8 + e

  // ---- build bf16 B-fragments: frg[ks][blade] = {bf16(x[lm][c(e)][blade])}_{e=0..7} ----
  // float for (e, blade): float4 idx = 2e + (blade>=4), comp = blade&3
  uint4 frg[2][8];
  #pragma unroll
  for (int b=0; b<8; ++b){
    const int hb = b >> 2, c = b & 3;
    frg[0][b].x = cvtpk(fc(va[0+hb],c),  fc(va[2+hb],c));
    frg[0][b].y = cvtpk(fc(va[4+hb],c),  fc(va[6+hb],c));
    frg[0][b].z = cvtpk(fc(va[8+hb],c),  fc(va[10+hb],c));
    frg[0][b].w = cvtpk(fc(va[12+hb],c), fc(va[14+hb],c));
    frg[1][b].x = cvtpk(fc(vb[0+hb],c),  fc(vb[2+hb],c));
    frg[1][b].y = cvtpk(fc(vb[4+hb],c),  fc(vb[6+hb],c));
    frg[1][b].z = cvtpk(fc(vb[8+hb],c),  fc(vb[10+hb],c));
    frg[1][b].w = cvtpk(fc(vb[12+hb],c), fc(vb[14+hb],c));
  }

  // ---- stage 1 + GP fused per ch-tile (cc-outer keeps VGPR low) ----
  const uint4* w1f = reinterpret_cast<const uint4*>(w1p);
  #pragma unroll
  for (int cc=0; cc<2; ++cc){
    const int cht = w + cc*4;
    f32x4 acc1[8];
    #pragma unroll
    for (int b=0; b<8; ++b) acc1[b] = (f32x4){0.f,0.f,0.f,0.f};

    #pragma unroll
    for (int g4=0; g4<4; ++g4){
      #pragma unroll
      for (int ks=0; ks<2; ++ks){
        uint4 wu = w1f[((g4*2+ks)*8 + cht)*64 + l];
        bf16x8 wv = __builtin_bit_cast(bf16x8, wu);
        #pragma unroll
        for (int bi=0; bi<3; ++bi){
          if (bi >= BCNT[g4]) break;
          const int blade = BSTART[g4] + bi;
          bf16x8 xv = __builtin_bit_cast(bf16x8, frg[ks][blade]);
          acc1[blade] = __builtin_amdgcn_mfma_f32_16x16x32_bf16(wv, xv, acc1[blade], 0,0,0);
        }
      }
    }

    // GP (half-scale) for this ch-tile; packed bf16 G writes (swizzled)
    const float4 b14 = reinterpret_cast<const float4*>(b1)[cht*4 + lh];
    const float bb[4] = {b14.x, b14.y, b14.z, b14.w};
    uint32_t lo[8], hi[8];
    #pragma unroll
    for (int rp=0; rp<2; ++rp){
      float ga[8], gb[8];
      {
        float h[8];
        #pragma unroll
        for (int b=0;b<8;b++) h[b] = acc1[b][rp*2+0];
        h[0] += bb[rp*2+0];
        gprod_half(h, ga);
      }
      {
        float h[8];
        #pragma unroll
        for (int b=0;b<8;b++) h[b] = acc1[b][rp*2+1];
        h[0] += bb[rp*2+1];
        gprod_half(h, gb);
      }
      #pragma unroll
      for (int b=0;b<8;b++){
        uint32_t v = cvtpk(ga[b], gb[b]);
        if (rp==0) lo[b] = v; else hi[b] = v;
      }
    }
    const int chByte = (cht*16 + lh*4) << 1;
    #pragma unroll
    for (int b=0;b<8;b++){
      uint2 v; v.x = lo[b]; v.y = hi[b];
      *reinterpret_cast<uint2*>(SH + ((((lm*8+b)<<8) + chByte) ^ xk)) = v;
    }
  }
  __syncthreads();                                   // bar1: G ready

  // ---- stage 2: Y[pos][oc] = G * W2   (A = G frag from LDS, B = W2 frag), wave w = oc-tile
  f32x4 acc2[8];
  #pragma unroll
  for (int b=0; b<8; ++b) acc2[b] = (f32x4){0.f,0.f,0.f,0.f};

  const uint4* w2f = reinterpret_cast<const uint4*>(w2p);
  #pragma unroll
  for (int ks=0; ks<4; ++ks){
    #pragma unroll
    for (int g4=0; g4<4; ++g4){
      uint4 wu = w2f[((g4*4+ks)*4 + w)*64 + l];
      bf16x8 wv = __builtin_bit_cast(bf16x8, wu);
      #pragma unroll
      for (int bi=0; bi<3; ++bi){
        if (bi >= BCNT[g4]) break;
        const int blade = BSTART[g4] + bi;
        bf16x8 gv = *reinterpret_cast<const bf16x8*>(
            SH + ((((lm*8+blade)<<8) + ((ks*32+lh*8)<<1)) ^ xk));
        acc2[blade] = __builtin_amdgcn_mfma_f32_16x16x32_bf16(gv, wv, acc2[blade], 0,0,0);
      }
    }
  }

  // ---- epilogue: bias, norms, per-position mean over 64 channels, scale, store
  const int oc = w*16 + lm;
  const float b2v  = b2[oc];
  const float aval = avec[oc];
  #pragma unroll
  for (int r=0; r<4; ++r) acc2[0][r] += b2v;

  float nrm[4];
  #pragma unroll
  for (int r=0; r<4; ++r) {
    float s = 0.f;
    #pragma unroll
    for (int b=0; b<8; ++b) s = fmaf(acc2[b][r], acc2[b][r], s);
    nrm[r] = sqrtf(s);
  }
  #pragma unroll
  for (int r=0; r<4; ++r) {
    float v = nrm[r];
    v += __shfl_xor(v, 1, 64);
    v += __shfl_xor(v, 2, 64);
    v += __shfl_xor(v, 4, 64);
    v += __shfl_xor(v, 8, 64);
    nrm[r] = v;                         // sum over this wave's 16 channels
  }
  __syncthreads();                                   // bar2: G reads done, redArr may alias
  if (lm == 0) {
    #pragma unroll
    for (int r=0; r<4; ++r) redArr[(lh*4 + r)*4 + w] = nrm[r];
  }
  __syncthreads();                                   // bar3: norms ready

  #pragma unroll
  for (int r=0; r<4; ++r) {
    const int pos = lh*4 + r;
    const float4 rr = *reinterpret_cast<const float4*>(redArr + pos*4);
    const float denom = (rr.x+rr.y+rr.z+rr.w) * (1.0f/64.0f) + 1e-6f;
    const float sc = aval / denom;
    float4 o0, o1;
    o0.x = acc2[0][r]*sc; o0.y = acc2[1][r]*sc; o0.z = acc2[2][r]*sc; o0.w = acc2[3][r]*sc;
    o1.x = acc2[4][r]*sc; o1.y = acc2[5][r]*sc; o1.z = acc2[6][r]*sc; o1.w = acc2[7][r]*sc;
    size_t P = (size_t)blockIdx.x*16 + pos;
    float4* op = reinterpret_cast<float4*>(out + (P*64 + (size_t)oc)*8);
    op[0] = o0; op[1] = o1;
  }
}

extern "C" void kernel_launch(void* const* d_in, const int* in_sizes, int n_in,
                              void* d_out, int out_size, void* d_ws, size_t ws_size,
                              hipStream_t stream)
{
  const float* x  = (const float*)d_in[0];
  const float* W1 = (const float*)d_in[1];
  const float* b1 = (const float*)d_in[2];
  const float* W2 = (const float*)d_in[3];
  const float* b2 = (const float*)d_in[4];
  const float* a  = (const float*)d_in[5];
  float* out = (float*)d_out;

  u16* w1p = (u16*)d_ws;          // 64 KB
  u16* w2p = w1p + 32768;         // 64 KB

  gp_prepack<<<256, 256, 0, stream>>>(W1, W2, w1p, w2p);
  gp_fused<<<2048, 256, 0, stream>>>(x, w1p, b1, w2p, b2, a, out);
}

// Round 7
// 41.554 us; speedup vs baseline: 1.4447x; 1.4447x over previous
//
#include <hip/hip_runtime.h>
#include <stdint.h>

typedef unsigned short u16;
typedef __attribute__((ext_vector_type(4))) float f32x4;
typedef __attribute__((ext_vector_type(8))) __bf16 bf16x8;

// ---- Cayley table for Cl(3,0), basis order [1,e1,e2,e3,e12,e13,e23,e123] ----
struct Cay { int idx[8][8]; float sgn[8][8]; };
constexpr int kOrder[8] = {0,1,2,4,3,5,6,7};
constexpr int ordpos(int m){ int r=-1; for(int i=0;i<8;i++) if(kOrder[i]==m) r=i; return r; }
constexpr Cay make_cay(){
  Cay c{};
  for(int ia=0; ia<8; ia++) for(int ib=0; ib<8; ib++){
    int a=kOrder[ia], b=kOrder[ib];
    int t=a>>1, tot=0;
    while(t){ int x=t&b; while(x){ tot+=x&1; x>>=1; } t>>=1; }
    c.idx[ia][ib]=ordpos(a^b);
    c.sgn[ia][ib]=(tot&1)?-1.0f:1.0f;
  }
  return c;
}
constexpr Cay CAY = make_cay();

// ---- squared-multivector GP at HALF SCALE for k!=0 (x2 folded into W2 grades 1..3) ----
struct GPTab { float dsgn[8]; int np; int pi[28]; int pj[28]; int pk[28]; float ps[28]; };
constexpr GPTab make_gptab(){
  GPTab t{};
  for (int i=0;i<8;i++) t.dsgn[i] = CAY.sgn[i][i];
  t.np = 0;
  for (int i=0;i<8;i++) for (int j=i+1;j<8;j++){
    float s = CAY.sgn[i][j] + CAY.sgn[j][i];      // in {-2,0,+2}
    if (s != 0.0f){ t.pi[t.np]=i; t.pj[t.np]=j; t.pk[t.np]=CAY.idx[i][j];
                    t.ps[t.np]=(s>0.f)?1.0f:-1.0f; t.np++; }
  }
  return t;
}
constexpr GPTab GPT = make_gptab();

__device__ __forceinline__ void gprod_half(const float* h, float* g){
  float g0 = h[0]*h[0];
  #pragma unroll
  for (int i=1;i<8;i++) g0 = fmaf(GPT.dsgn[i]>0.f ? h[i] : -h[i], h[i], g0);
  g[0] = g0;
  #pragma unroll
  for (int k=1;k<8;k++) g[k] = 0.f;
  #pragma unroll
  for (int t=0;t<GPT.np;t++)
    g[GPT.pk[t]] = fmaf(GPT.ps[t]>0.f ? h[GPT.pi[t]] : -h[GPT.pi[t]],
                        h[GPT.pj[t]], g[GPT.pk[t]]);
}

__device__ __forceinline__ u16 f2bf(float f){
  union { float f; uint32_t u; } v; v.f=f;
  uint32_t u=v.u;
  return (u16)((u + 0x7fffu + ((u>>16)&1u)) >> 16);   // RNE
}

__device__ __forceinline__ uint32_t cvtpk(float lo, float hi){
  uint32_t r;
  asm("v_cvt_pk_bf16_f32 %0, %1, %2" : "=v"(r) : "v"(lo), "v"(hi));
  return r;
}

// ---- weight repack ----
// w1p frag f=((g*2+ks)*8+ot): lane l, elem e -> W1[ot*16+(l&15)][ks*32+(l>>4)*8+e][g]
// w2p frag f=((g*4+ks)*4+ot): lane l, elem e -> W2[ot*16+(l&15)][ks*32+(l>>4)*8+e][g] * (g?2:1)
__global__ void gp_prepack(const float* __restrict__ W1, const float* __restrict__ W2,
                           u16* __restrict__ w1p, u16* __restrict__ w2p)
{
  int t = blockIdx.x*256 + threadIdx.x;   // 0..65535
  int e = t & 7, l = (t>>3)&63, f = t>>9;
  int lm = l & 15, lh = l >> 4;
  if (f < 64) {
    int g = f >> 4, ks = (f>>3)&1, ot = f&7;
    int o = ot*16 + lm, c = ks*32 + lh*8 + e;
    w1p[f*512 + l*8 + e] = f2bf(W1[(o*64 + c)*4 + g]);
  } else {
    int f2 = f - 64;
    int g = f2 >> 4, ks = (f2>>2)&3, ot = f2&3;
    int outc = ot*16 + lm, o = ks*32 + lh*8 + e;
    float sc = (g == 0) ? 1.0f : 2.0f;               // half-scale GP compensation
    w2p[f2*512 + l*8 + e] = f2bf(W2[(outc*128 + o)*4 + g] * sc);
  }
}

// LDS (exactly 32768 B):
//   X tile [pos16][blade8][cin64] bf16 aliases the low 16 KB of
//   G tile [pos16][blade8][ch128] bf16 (32 KB).  Both swizzled: byte ^= ((pos&7)<<4).
//   redArr[16][4] (256 B) aliases SH+0, used only after stage 2 (extra barrier).
__global__ __launch_bounds__(256,4) void gp_fused(
    const float* __restrict__ x, const u16* __restrict__ w1p,
    const float* __restrict__ b1, const u16* __restrict__ w2p,
    const float* __restrict__ b2, const float* __restrict__ avec,
    float* __restrict__ out)
{
  __shared__ __align__(16) char SH[32768];
  float* redArr = reinterpret_cast<float*>(SH);     // [pos][w], 16x4 floats

  const int tid = threadIdx.x;
  const int w  = tid >> 6;     // wave 0..3
  const int l  = tid & 63;
  const int lm = l & 15;
  const int lh = l >> 4;
  const int xk = (lm & 7) << 4;   // swizzle key for MFMA-operand reads (pos = lm)

  const uint4* w1f = reinterpret_cast<const uint4*>(w1p);
  const uint4* w2f = reinterpret_cast<const uint4*>(w2p);

  // ---- prefetch stage-1 weight frags for g4=0,1 (latency hides under staging+bar1)
  // w1r[(g4*2+ks)*2 + cc] = frag for (g4,ks), ch-tile w+4*cc
  uint4 w1r[8];
  #pragma unroll
  for (int i=0; i<4; ++i){          // i = g4*2+ks, g4 in {0,1}
    w1r[i*2+0] = w1f[(i*8 + w    )*64 + l];
    w1r[i*2+1] = w1f[(i*8 + w + 4)*64 + l];
  }

  // ---- stage X: 16 pos x 64 cin x 8 blades -> LDS, packed bf16 writes
  {
    const int cp = tid & 31;          // c-pair: c0 = 2*cp
    const int pr = tid >> 5;          // 0..7
    const float4* xt = reinterpret_cast<const float4*>(x) + (size_t)blockIdx.x * 2048;
    #pragma unroll
    for (int it=0; it<2; ++it){
      const int p = pr + it*8;
      const float4* src = xt + p*128 + cp*4;
      float4 v0 = src[0], v1 = src[1], v2 = src[2], v3 = src[3];
      uint32_t pk[8];
      pk[0]=cvtpk(v0.x,v2.x); pk[1]=cvtpk(v0.y,v2.y); pk[2]=cvtpk(v0.z,v2.z); pk[3]=cvtpk(v0.w,v2.w);
      pk[4]=cvtpk(v1.x,v3.x); pk[5]=cvtpk(v1.y,v3.y); pk[6]=cvtpk(v1.z,v3.z); pk[7]=cvtpk(v1.w,v3.w);
      const int xo = (p & 7) << 4;
      #pragma unroll
      for (int b=0;b<8;b++)
        *reinterpret_cast<uint32_t*>(SH + ((((p*8+b)<<7) + (cp<<2)) ^ xo)) = pk[b];
    }
  }
  __syncthreads();                                   // bar1: X ready

  constexpr int BSTART[4] = {0,1,4,7};
  constexpr int BCNT[4]   = {1,3,3,1};

  // ---- stage 1: H[ch][pos] = W1 * X   (A = W1 frag, B = X frag)
  f32x4 acc1[2][8];
  #pragma unroll
  for (int cc=0; cc<2; ++cc)
    #pragma unroll
    for (int b=0; b<8; ++b)
      acc1[cc][b] = (f32x4){0.f,0.f,0.f,0.f};

  #pragma unroll
  for (int g4=0; g4<4; ++g4){
    #pragma unroll
    for (int ks=0; ks<2; ++ks){
      uint4 wa, wb;
      if (g4 < 2){ wa = w1r[(g4*2+ks)*2+0]; wb = w1r[(g4*2+ks)*2+1]; }
      else { wa = w1f[((g4*2+ks)*8 + w    )*64 + l];
             wb = w1f[((g4*2+ks)*8 + w + 4)*64 + l]; }
      bf16x8 wav = __builtin_bit_cast(bf16x8, wa);
      bf16x8 wbv = __builtin_bit_cast(bf16x8, wb);
      #pragma unroll
      for (int bi=0; bi<3; ++bi){
        if (bi >= BCNT[g4]) break;
        const int blade = BSTART[g4] + bi;
        bf16x8 xv = *reinterpret_cast<const bf16x8*>(
            SH + ((((lm*8+blade)<<7) + ((ks*32+lh*8)<<1)) ^ xk));
        acc1[0][blade] = __builtin_amdgcn_mfma_f32_16x16x32_bf16(wav, xv, acc1[0][blade], 0,0,0);
        acc1[1][blade] = __builtin_amdgcn_mfma_f32_16x16x32_bf16(wbv, xv, acc1[1][blade], 0,0,0);
      }
    }
  }
  __syncthreads();                                   // bar2: X reads done before G overwrite

  // ---- GP (half-scale) per (pos=lm, ch) in-register; packed bf16 G writes ----
  #pragma unroll
  for (int cc=0; cc<2; ++cc){
    const int cht = w + cc*4;
    const float4 b14 = reinterpret_cast<const float4*>(b1)[cht*4 + lh];
    const float bb[4] = {b14.x, b14.y, b14.z, b14.w};
    uint32_t lo[8], hi[8];
    #pragma unroll
    for (int rp=0; rp<2; ++rp){
      float ga[8], gb[8];
      {
        float h[8];
        #pragma unroll
        for (int b=0;b<8;b++) h[b] = acc1[cc][b][rp*2+0];
        h[0] += bb[rp*2+0];
        gprod_half(h, ga);
      }
      {
        float h[8];
        #pragma unroll
        for (int b=0;b<8;b++) h[b] = acc1[cc][b][rp*2+1];
        h[0] += bb[rp*2+1];
        gprod_half(h, gb);
      }
      #pragma unroll
      for (int b=0;b<8;b++){
        uint32_t v = cvtpk(ga[b], gb[b]);
        if (rp==0) lo[b] = v; else hi[b] = v;
      }
    }
    const int chByte = (cht*16 + lh*4) << 1;
    #pragma unroll
    for (int b=0;b<8;b++){
      uint2 v; v.x = lo[b]; v.y = hi[b];
      *reinterpret_cast<uint2*>(SH + ((((lm*8+b)<<8) + chByte) ^ xk)) = v;
    }
  }

  // ---- prefetch stage-2 weight frags for ks=0,1 (latency hides under GP tail + bar3)
  uint4 w2r[8];
  #pragma unroll
  for (int ks=0; ks<2; ++ks)
    #pragma unroll
    for (int g4=0; g4<4; ++g4)
      w2r[ks*4+g4] = w2f[((g4*4+ks)*4 + w)*64 + l];

  __syncthreads();                                   // bar3: G ready

  // ---- stage 2: Y[pos][oc] = G * W2   (A = G frag, B = W2 frag), wave w = oc-tile
  f32x4 acc2[8];
  #pragma unroll
  for (int b=0; b<8; ++b) acc2[b] = (f32x4){0.f,0.f,0.f,0.f};

  #pragma unroll
  for (int ks=0; ks<4; ++ks){
    #pragma unroll
    for (int g4=0; g4<4; ++g4){
      uint4 wu;
      if (ks < 2) wu = w2r[ks*4+g4];
      else        wu = w2f[((g4*4+ks)*4 + w)*64 + l];
      bf16x8 wv = __builtin_bit_cast(bf16x8, wu);
      #pragma unroll
      for (int bi=0; bi<3; ++bi){
        if (bi >= BCNT[g4]) break;
        const int blade = BSTART[g4] + bi;
        bf16x8 gv = *reinterpret_cast<const bf16x8*>(
            SH + ((((lm*8+blade)<<8) + ((ks*32+lh*8)<<1)) ^ xk));
        acc2[blade] = __builtin_amdgcn_mfma_f32_16x16x32_bf16(gv, wv, acc2[blade], 0,0,0);
      }
    }
  }

  // ---- epilogue: bias, norms, per-position mean over 64 channels, scale, store
  const int oc = w*16 + lm;
  const float b2v  = b2[oc];
  const float aval = avec[oc];
  #pragma unroll
  for (int r=0; r<4; ++r) acc2[0][r] += b2v;

  float nrm[4];
  #pragma unroll
  for (int r=0; r<4; ++r) {
    float s = 0.f;
    #pragma unroll
    for (int b=0; b<8; ++b) s = fmaf(acc2[b][r], acc2[b][r], s);
    nrm[r] = sqrtf(s);
  }
  #pragma unroll
  for (int r=0; r<4; ++r) {
    float v = nrm[r];
    v += __shfl_xor(v, 1, 64);
    v += __shfl_xor(v, 2, 64);
    v += __shfl_xor(v, 4, 64);
    v += __shfl_xor(v, 8, 64);
    nrm[r] = v;                         // sum over this wave's 16 channels
  }
  __syncthreads();                                   // bar4: G reads done, redArr may alias
  if (lm == 0) {
    #pragma unroll
    for (int r=0; r<4; ++r) redArr[(lh*4 + r)*4 + w] = nrm[r];
  }
  __syncthreads();                                   // bar5: norms ready

  #pragma unroll
  for (int r=0; r<4; ++r) {
    const int pos = lh*4 + r;
    const float4 rr = *reinterpret_cast<const float4*>(redArr + pos*4);
    const float denom = (rr.x+rr.y+rr.z+rr.w) * (1.0f/64.0f) + 1e-6f;
    const float sc = aval * __builtin_amdgcn_rcpf(denom);
    f32x4 o0, o1;
    o0[0] = acc2[0][r]*sc; o0[1] = acc2[1][r]*sc; o0[2] = acc2[2][r]*sc; o0[3] = acc2[3][r]*sc;
    o1[0] = acc2[4][r]*sc; o1[1] = acc2[5][r]*sc; o1[2] = acc2[6][r]*sc; o1[3] = acc2[7][r]*sc;
    size_t P = (size_t)blockIdx.x*16 + pos;
    f32x4* op = reinterpret_cast<f32x4*>(out + (P*64 + (size_t)oc)*8);
    __builtin_nontemporal_store(o0, op);
    __builtin_nontemporal_store(o1, op + 1);
  }
}

extern "C" void kernel_launch(void* const* d_in, const int* in_sizes, int n_in,
                              void* d_out, int out_size, void* d_ws, size_t ws_size,
                              hipStream_t stream)
{
  const float* x  = (const float*)d_in[0];
  const float* W1 = (const float*)d_in[1];
  const float* b1 = (const float*)d_in[2];
  const float* W2 = (const float*)d_in[3];
  const float* b2 = (const float*)d_in[4];
  const float* a  = (const float*)d_in[5];
  float* out = (float*)d_out;

  u16* w1p = (u16*)d_ws;          // 64 KB
  u16* w2p = w1p + 32768;         // 64 KB

  gp_prepack<<<256, 256, 0, stream>>>(W1, W2, w1p, w2p);
  gp_fused<<<2048, 256, 0, stream>>>(x, w1p, b1, w2p, b2, a, out);
}